// Round 1
// baseline (5879.308 us; speedup 1.0000x reference)
//
#include <hip/hip_runtime.h>
#include <stdint.h>
#include <math.h>

// Problem constants (fixed by the reference): B=2, H=16, S=2048, D=64
#define BB 2
#define HH 16
#define SS 2048
#define DD 64
#define TQ 16   // queries per block
#define TK 16   // keys per k-tile
#define NT 512  // threads per block (8 waves)

__device__ __forceinline__ float bflo(unsigned int u){ return __uint_as_float(u << 16); }
__device__ __forceinline__ float bfhi(unsigned int u){ return __uint_as_float(u & 0xffff0000u); }
__device__ __forceinline__ float bfs(unsigned short s){ return __uint_as_float(((unsigned int)s) << 16); }
__device__ __forceinline__ unsigned short f2bf(float f){
  unsigned int u = __float_as_uint(f);
  u += 0x7fffu + ((u >> 16) & 1u);   // round-to-nearest-even
  return (unsigned short)(u >> 16);
}

// ---------------------------------------------------------------------------
// Mask dtype detection: harness converts a jax bool array to *some* dtype.
// Classify from the first 4096 32-bit words (first 16 KB; mask >= 128 MB so
// always in bounds). With P(mask)=0.1 the signatures are unambiguous
// (P[wrong class] ~ 0.73^4096 ~ 0).
//   mode 0: int32  (every word 0 or 1)
//   mode 1: int8   (bytes 0/1 packed -> words like 0x00010001)
//   mode 2: float32 (words 0x00000000 / 0x3F800000)
//   mode 3: int64  (even words 0/1, odd words all 0)
// ---------------------------------------------------------------------------
__global__ void detect_mask_mode(const unsigned int* __restrict__ mw, int* __restrict__ mode_out){
  __shared__ int a32, af, a64;
  const int t = threadIdx.x;
  if (t == 0){ a32 = 1; af = 1; a64 = 1; }
  __syncthreads();
  int ok32 = 1, okf = 1, ok64 = 1;
  for (int idx = t; idx < 4096; idx += 256){
    const unsigned int w = mw[idx];
    if (w > 1u) ok32 = 0;
    if (w != 0u && w != 0x3F800000u) okf = 0;
    if ((idx & 1) ? (w != 0u) : (w > 1u)) ok64 = 0;
  }
  if (!ok32) atomicAnd(&a32, 0);
  if (!okf)  atomicAnd(&af, 0);
  if (!ok64) atomicAnd(&a64, 0);
  __syncthreads();
  if (t == 0){
    int mode;
    if (a64)      mode = 3;   // int64 signature (subset of int32 signature, test first)
    else if (a32) mode = 0;
    else if (af)  mode = 2;
    else          mode = 1;
    *mode_out = mode;
  }
}

__device__ __forceinline__ bool mask_at(const void* mask, size_t midx, int mode){
  if (mode == 0) return ((const int*)mask)[midx] != 0;
  if (mode == 1) return ((const unsigned char*)mask)[midx] != 0;
  if (mode == 2) return ((const float*)mask)[midx] != 0.0f;
  return ((const int*)mask)[midx * 2] != 0;   // int64: low word suffices for bool
}

// ---------------------------------------------------------------------------
// Fused kernel. Block = (q-tile of 16, batch b). 512 threads = 8 waves.
// Per k-tile of 16 keys (all 16 heads together):
//   1) stage K[b,:,k0:k0+16,:] -> LDS as bf16 (row-padded to 68 to spread banks)
//   2) scores s[h][i][kk] = dot64(Q,K)/8 -> LDS bf16
//      thread (h = t>>5, kk = j&15, ihalf = j>>4) computes 8 i's;
//      Q read from global: 16-lane broadcast float4 (L1-resident 64KB tile)
//   3) softmax over h per (i,kk): 256 threads, each owns one (i,kk);
//      mask applied here (single coalesced-ish read of each mask element)
//   4) PV: thread (h = t>>5, dd = j) owns d-pair; coalesced float2 V loads,
//      broadcast bf16 weight reads, fp32 accumulation in registers
// Output epilogue: [B,S,H,D] coalesced float2 stores.
// ---------------------------------------------------------------------------
__global__ __launch_bounds__(NT) void sdpa_headsoftmax_kernel(
    const float* __restrict__ Q, const float* __restrict__ K, const float* __restrict__ V,
    const void* __restrict__ mask, const int* __restrict__ modep, float* __restrict__ out)
{
  __shared__ unsigned short Klds[HH * TK * 68];   // 34816 B, row stride 68 (pad)
  __shared__ unsigned short Slds[HH * TQ * TK];   //  8192 B

  const int t  = threadIdx.x;
  const int b  = blockIdx.y;
  const int q0 = blockIdx.x * TQ;
  const int mode = *modep;

  const int h = t >> 5;        // head owned in score/PV phases
  const int j = t & 31;

  // score-phase sub-mapping
  const int kk_s  = j & 15;
  const int ihalf = j >> 4;

  // staging sub-mapping: 256 rows (h*16+kk), 2 threads per row
  const int r_st  = t >> 1;
  const int half  = t & 1;
  const int h_st  = r_st >> 4;
  const int kk_st = r_st & 15;

  // PV / output mapping: d-pair per thread
  const int dd = j;

  float2 o2[TQ];
  #pragma unroll
  for (int i = 0; i < TQ; ++i){ o2[i].x = 0.f; o2[i].y = 0.f; }

  for (int kt = 0; kt < SS / TK; ++kt){
    const int k0 = kt * TK;

    // ---- 1) stage K tile: fp32 global (coalesced float4) -> bf16 LDS ----
    {
      const float* src = K + ((size_t)(b * HH + h_st) * SS + (size_t)(k0 + kk_st)) * DD + half * 32;
      unsigned short* dst = &Klds[r_st * 68 + half * 32];
      #pragma unroll
      for (int c = 0; c < 8; ++c){
        const float4 v4 = *(const float4*)(src + c * 4);
        dst[c * 4 + 0] = f2bf(v4.x);
        dst[c * 4 + 1] = f2bf(v4.y);
        dst[c * 4 + 2] = f2bf(v4.z);
        dst[c * 4 + 3] = f2bf(v4.w);
      }
    }
    __syncthreads();

    // ---- 2) scores ----
    {
      float acc[8];
      #pragma unroll
      for (int ii = 0; ii < 8; ++ii) acc[ii] = 0.f;
      const float* qbase = Q + ((size_t)(b * HH + h) * SS + (size_t)(q0 + ihalf * 8)) * DD;
      const unsigned short* krow = &Klds[(h * 16 + kk_s) * 68];
      #pragma unroll 4
      for (int d4 = 0; d4 < 16; ++d4){
        const uint2 kp = *(const uint2*)(krow + d4 * 4);
        const float k0f = bflo(kp.x), k1f = bfhi(kp.x);
        const float k2f = bflo(kp.y), k3f = bfhi(kp.y);
        #pragma unroll
        for (int ii = 0; ii < 8; ++ii){
          const float4 q4 = *(const float4*)(qbase + ii * DD + d4 * 4);
          acc[ii] = fmaf(q4.w, k3f, fmaf(q4.z, k2f, fmaf(q4.y, k1f, fmaf(q4.x, k0f, acc[ii]))));
        }
      }
      #pragma unroll
      for (int ii = 0; ii < 8; ++ii){
        Slds[(h * TQ + ihalf * 8 + ii) * TK + kk_s] = f2bf(acc[ii] * 0.125f);
      }
    }
    __syncthreads();

    // ---- 3) masked softmax over heads, in place ----
    if (t < TQ * TK){
      const int i  = t >> 4;
      const int kk = t & 15;
      float sv[HH];
      float m = -INFINITY;
      #pragma unroll
      for (int hh = 0; hh < HH; ++hh){
        float f = bfs(Slds[(hh * TQ + i) * TK + kk]);
        const size_t midx = ((size_t)(b * HH + hh) * SS + (size_t)(q0 + i)) * SS + (size_t)(k0 + kk);
        if (mask_at(mask, midx, mode)) f = -INFINITY;
        sv[hh] = f;
        m = fmaxf(m, f);
      }
      float sum = 0.f;
      #pragma unroll
      for (int hh = 0; hh < HH; ++hh){
        const float e = (sv[hh] == -INFINITY) ? 0.f : __expf(sv[hh] - m);
        sv[hh] = e;
        sum += e;
      }
      const float rinv = (sum > 0.f) ? (1.f / sum) : 0.f;   // all-masked -> zero weights
      #pragma unroll
      for (int hh = 0; hh < HH; ++hh){
        Slds[(hh * TQ + i) * TK + kk] = f2bf(sv[hh] * rinv);
      }
    }
    __syncthreads();

    // ---- 4) PV accumulate ----
    {
      const float* vbase = V + ((size_t)(b * HH + h) * SS + (size_t)k0) * DD + dd * 2;
      #pragma unroll
      for (int kq = 0; kq < 4; ++kq){
        float2 vv[4];
        #pragma unroll
        for (int c = 0; c < 4; ++c) vv[c] = *(const float2*)(vbase + (size_t)(kq * 4 + c) * DD);
        #pragma unroll
        for (int i = 0; i < TQ; ++i){
          const uint2 wp = *(const uint2*)&Slds[(h * TQ + i) * TK + kq * 4];
          const float w0 = bflo(wp.x), w1 = bfhi(wp.x);
          const float w2 = bflo(wp.y), w3 = bfhi(wp.y);
          o2[i].x = fmaf(w0, vv[0].x, fmaf(w1, vv[1].x, fmaf(w2, vv[2].x, fmaf(w3, vv[3].x, o2[i].x))));
          o2[i].y = fmaf(w0, vv[0].y, fmaf(w1, vv[1].y, fmaf(w2, vv[2].y, fmaf(w3, vv[3].y, o2[i].y))));
        }
      }
    }
    __syncthreads();
  }

  // ---- epilogue: out[b, q, h, d] ----
  #pragma unroll
  for (int i = 0; i < TQ; ++i){
    float* op = out + ((size_t)(b * SS + (size_t)(q0 + i)) * HH + h) * DD + dd * 2;
    *(float2*)op = o2[i];
  }
}

extern "C" void kernel_launch(void* const* d_in, const int* in_sizes, int n_in,
                              void* d_out, int out_size, void* d_ws, size_t ws_size,
                              hipStream_t stream)
{
  const float* Q = (const float*)d_in[0];
  const float* K = (const float*)d_in[1];
  const float* V = (const float*)d_in[2];
  const void* mask = d_in[3];
  // d_in[4] = head_dim scalar (fixed at 64; unused)

  int* mode_ptr = (int*)d_ws;
  detect_mask_mode<<<1, 256, 0, stream>>>((const unsigned int*)mask, mode_ptr);

  dim3 grid(SS / TQ, BB);
  sdpa_headsoftmax_kernel<<<grid, NT, 0, stream>>>(Q, K, V, mask, mode_ptr, (float*)d_out);
}

// Round 2
// 1087.135 us; speedup vs baseline: 5.4081x; 5.4081x over previous
//
#include <hip/hip_runtime.h>
#include <stdint.h>
#include <math.h>

// Problem constants: B=2, H=16, S=2048, D=64
#define BB 2
#define HH 16
#define SS 2048
#define DD 64
#define HSS ((size_t)SS * SS)        // mask per-head stride (elements)
#define QE  ((size_t)BB * HH * SS * DD)  // 4,194,304 elements per tensor

typedef __attribute__((ext_vector_type(8))) short short8;   // bf16x8 MFMA frag
typedef __attribute__((ext_vector_type(4))) float float4v;  // fp32x4 accum

__device__ __forceinline__ float bflo(unsigned int u){ return __uint_as_float(u << 16); }
__device__ __forceinline__ float bfhi(unsigned int u){ return __uint_as_float(u & 0xffff0000u); }
__device__ __forceinline__ unsigned short f2bf(float f){
  unsigned int u = __float_as_uint(f);
  u += 0x7fffu + ((u >> 16) & 1u);   // RNE
  return (unsigned short)(u >> 16);
}
__device__ __forceinline__ unsigned int pk2(float lo, float hi){
  return ((unsigned int)f2bf(hi) << 16) | (unsigned int)f2bf(lo);
}

// ---------------------------------------------------------------------------
// Mask dtype detection (unchanged from round 0 — it worked).
// ---------------------------------------------------------------------------
__global__ void detect_mask_mode(const unsigned int* __restrict__ mw, int* __restrict__ mode_out){
  __shared__ int a32, af, a64;
  const int t = threadIdx.x;
  if (t == 0){ a32 = 1; af = 1; a64 = 1; }
  __syncthreads();
  int ok32 = 1, okf = 1, ok64 = 1;
  for (int idx = t; idx < 4096; idx += 256){
    const unsigned int w = mw[idx];
    if (w > 1u) ok32 = 0;
    if (w != 0u && w != 0x3F800000u) okf = 0;
    if ((idx & 1) ? (w != 0u) : (w > 1u)) ok64 = 0;
  }
  if (!ok32) atomicAnd(&a32, 0);
  if (!okf)  atomicAnd(&af, 0);
  if (!ok64) atomicAnd(&a64, 0);
  __syncthreads();
  if (t == 0){
    int mode;
    if (a64)      mode = 3;
    else if (a32) mode = 0;
    else if (af)  mode = 2;
    else          mode = 1;
    *mode_out = mode;
  }
}

// ---------------------------------------------------------------------------
// Prep: fp32 -> bf16 copy (with optional scale; Q gets 1/sqrt(64)=0.125 folded in)
// ---------------------------------------------------------------------------
__global__ void conv_bf16_kernel(const float* __restrict__ src, unsigned short* __restrict__ dst, float scale){
  const size_t i = ((size_t)blockIdx.x * 256 + threadIdx.x) * 8;
  const float4 a = *(const float4*)(src + i);
  const float4 b = *(const float4*)(src + i + 4);
  uint4 o;
  o.x = pk2(a.x * scale, a.y * scale);
  o.y = pk2(a.z * scale, a.w * scale);
  o.z = pk2(b.x * scale, b.y * scale);
  o.w = pk2(b.z * scale, b.w * scale);
  *(uint4*)(dst + i) = o;
}

// ---------------------------------------------------------------------------
// Prep: V[b,h,k,d] fp32 -> Vt[b,h,d,k] bf16 (64x64 LDS tile transpose)
// ---------------------------------------------------------------------------
__global__ void transp_v_kernel(const float* __restrict__ V, unsigned short* __restrict__ Vt){
  __shared__ unsigned short tile[64][66];
  const int t  = threadIdx.x;
  const int kt = blockIdx.x & 31;    // k-tile of 64
  const int bh = blockIdx.x >> 5;    // b*16+h
  {
    const int kr = t >> 2, dc = (t & 3) * 16;
    const float* src = V + ((size_t)bh * SS + (size_t)(kt * 64 + kr)) * DD + dc;
    #pragma unroll
    for (int c = 0; c < 4; ++c){
      const float4 v = *(const float4*)(src + c * 4);
      tile[kr][dc + c * 4 + 0] = f2bf(v.x);
      tile[kr][dc + c * 4 + 1] = f2bf(v.y);
      tile[kr][dc + c * 4 + 2] = f2bf(v.z);
      tile[kr][dc + c * 4 + 3] = f2bf(v.w);
    }
  }
  __syncthreads();
  {
    const int dr = t >> 2, kc = (t & 3) * 16;
    unsigned short* dst = Vt + ((size_t)bh * DD + dr) * SS + kt * 64 + kc;
    unsigned int w[8];
    #pragma unroll
    for (int p = 0; p < 8; ++p){
      w[p] = (unsigned int)tile[kc + 2*p][dr] | ((unsigned int)tile[kc + 2*p + 1][dr] << 16);
    }
    uint4 o0 = { w[0], w[1], w[2], w[3] };
    uint4 o1 = { w[4], w[5], w[6], w[7] };
    *(uint4*)(dst)     = o0;
    *(uint4*)(dst + 8) = o1;
  }
}

// ---------------------------------------------------------------------------
// Main fused kernel.
// Block: 512 thr = 8 waves; one 16-query tile, batch b, k-chunk kc (split-k=2).
// Per k-step of 128 keys:
//  - wave w: scores for k-sub-tile w (16 keys), ALL 16 heads via 16x16x32 MFMA
//    (A=Q frag, B=K frag, both contiguous 16B bf16 global loads).
//    C-layout puts all 16 h-values of a (q,k) in one lane -> in-lane softmax.
//  - mask applied as -inf pre-pack (scores kept packed bf16x2: 32 VGPRs).
//  - softmax over h in registers; W -> LDS [h][q][k^swz] bf16, exactly 64 KB.
//  - barrier; wave w owns heads {2w,2w+1}: O += W @ V via MFMA, B-frags are
//    contiguous 16B loads from pre-transposed Vt. barrier.
// Epilogue: unsafeAtomicAdd into zeroed out[b,q,h,d] (split-k partial sums).
// ---------------------------------------------------------------------------
__global__ __launch_bounds__(512, 2) void attn_main_kernel(
    const unsigned short* __restrict__ Qb, const unsigned short* __restrict__ Kb,
    const unsigned short* __restrict__ Vt, const void* __restrict__ mask,
    const int* __restrict__ modep, float* __restrict__ out)
{
  __shared__ unsigned short W[HH * 16 * 128];   // 65536 B

  const int t = threadIdx.x;
  const int wave = t >> 6, lane = t & 63, quad = lane >> 4, l16 = lane & 15;
  const int b = blockIdx.y, q0 = blockIdx.x * 16, kc = blockIdx.z;

  const int mode = *modep;
  const bool bmode = (mode == 1);
  const int msh = (mode == 3) ? 1 : 0;    // dword-index shift (int64 low word)
  const unsigned int*  mw = (const unsigned int*)mask;
  const unsigned char* mby = (const unsigned char*)mask;

  float4v O[2][4];
  #pragma unroll
  for (int i = 0; i < 2; ++i)
    #pragma unroll
    for (int j = 0; j < 4; ++j) O[i][j] = (float4v){0.f, 0.f, 0.f, 0.f};

  const unsigned short* qbase = Qb + ((size_t)(b * HH) * SS + (size_t)(q0 + l16)) * DD + quad * 8;

  #pragma unroll 1
  for (int ks = 0; ks < 8; ++ks){
    const int k0  = (kc * 8 + ks) * 128;
    const int k0w = k0 + wave * 16;

    // ---- scores: all 16 heads for this wave's 16-key sub-tile ----
    unsigned int sp[HH][2];
    const unsigned short* kbase = Kb + ((size_t)(b * HH) * SS + (size_t)(k0w + l16)) * DD + quad * 8;
    const size_t mb0 = ((size_t)(b * HH) * SS + (size_t)(q0 + quad * 4)) * SS + (size_t)(k0w + l16);

    #pragma unroll
    for (int h = 0; h < HH; ++h){
      const unsigned short* qp = qbase + (size_t)h * (SS * DD);
      const unsigned short* kp = kbase + (size_t)h * (SS * DD);
      const short8 a0 = *(const short8*)(qp);
      const short8 a1 = *(const short8*)(qp + 32);
      const short8 b0 = *(const short8*)(kp);
      const short8 b1 = *(const short8*)(kp + 32);
      float4v c = (float4v){0.f, 0.f, 0.f, 0.f};
      c = __builtin_amdgcn_mfma_f32_16x16x32_bf16(a0, b0, c, 0, 0, 0);
      c = __builtin_amdgcn_mfma_f32_16x16x32_bf16(a1, b1, c, 0, 0, 0);

      // mask -> -inf (scale already folded into Qb)
      unsigned int mv[4];
      const size_t mi = mb0 + (size_t)h * HSS;
      if (!bmode){
        #pragma unroll
        for (int r = 0; r < 4; ++r) mv[r] = mw[(mi + (size_t)r * SS) << msh];
      } else {
        #pragma unroll
        for (int r = 0; r < 4; ++r) mv[r] = (unsigned int)mby[mi + (size_t)r * SS];
      }
      #pragma unroll
      for (int r = 0; r < 4; ++r) if (mv[r]) c[r] = -INFINITY;

      sp[h][0] = pk2(c[0], c[1]);
      sp[h][1] = pk2(c[2], c[3]);
    }

    // ---- in-lane softmax over heads, write W to LDS ----
    #pragma unroll
    for (int r = 0; r < 4; ++r){
      const int row = quad * 4 + r;
      float sv[HH];
      float m = -INFINITY;
      #pragma unroll
      for (int h = 0; h < HH; ++h){
        const unsigned int u = sp[h][r >> 1];
        const float f = (r & 1) ? bfhi(u) : bflo(u);
        sv[h] = f;
        m = fmaxf(m, f);
      }
      float sum = 0.f;
      #pragma unroll
      for (int h = 0; h < HH; ++h){
        const float e = (sv[h] != -INFINITY) ? __expf(sv[h] - m) : 0.f;
        sv[h] = e;
        sum += e;
      }
      const float rinv = (sum > 0.f) ? (1.0f / sum) : 0.f;
      const int kloc = wave * 16 + l16;
      const int col  = kloc ^ ((row & 7) << 3);     // XOR swizzle, keeps 16B blocks intact
      #pragma unroll
      for (int h = 0; h < HH; ++h){
        W[h * 2048 + row * 128 + col] = f2bf(sv[h] * rinv);
      }
    }
    __syncthreads();

    // ---- PV: this wave owns heads 2w, 2w+1 ----
    #pragma unroll
    for (int hh = 0; hh < 2; ++hh){
      const int h = wave * 2 + hh;
      const unsigned short* vb = Vt + ((size_t)(b * HH + h) * DD + l16) * SS + k0 + quad * 8;
      #pragma unroll
      for (int kr = 0; kr < 4; ++kr){
        const int kidx = kr * 32 + quad * 8;
        const short8 aw = *(const short8*)&W[h * 2048 + l16 * 128 + (kidx ^ ((l16 & 7) << 3))];
        #pragma unroll
        for (int dt = 0; dt < 4; ++dt){
          const short8 bv = *(const short8*)(vb + (size_t)dt * 16 * SS + kr * 32);
          O[hh][dt] = __builtin_amdgcn_mfma_f32_16x16x32_bf16(aw, bv, O[hh][dt], 0, 0, 0);
        }
      }
    }
    __syncthreads();
  }

  // ---- epilogue: atomic accumulate split-k partials ----
  #pragma unroll
  for (int hh = 0; hh < 2; ++hh){
    const int h = wave * 2 + hh;
    #pragma unroll
    for (int dt = 0; dt < 4; ++dt){
      #pragma unroll
      for (int r = 0; r < 4; ++r){
        float* op = out + (((size_t)b * SS + (size_t)(q0 + quad * 4 + r)) * HH + h) * DD + dt * 16 + l16;
        unsafeAtomicAdd(op, O[hh][dt][r]);
      }
    }
  }
}

extern "C" void kernel_launch(void* const* d_in, const int* in_sizes, int n_in,
                              void* d_out, int out_size, void* d_ws, size_t ws_size,
                              hipStream_t stream)
{
  const float* Q = (const float*)d_in[0];
  const float* K = (const float*)d_in[1];
  const float* V = (const float*)d_in[2];
  const void* mask = d_in[3];

  uintptr_t base = (uintptr_t)d_ws;
  int* mode_ptr       = (int*)base;
  unsigned short* Qb  = (unsigned short*)(base + 64);
  unsigned short* Kb  = Qb + QE;
  unsigned short* Vt  = Kb + QE;

  detect_mask_mode<<<1, 256, 0, stream>>>((const unsigned int*)mask, mode_ptr);
  conv_bf16_kernel<<<2048, 256, 0, stream>>>(Q, Qb, 0.125f);   // fold 1/sqrt(D)
  conv_bf16_kernel<<<2048, 256, 0, stream>>>(K, Kb, 1.0f);
  transp_v_kernel<<<BB * HH * (SS / 64), 256, 0, stream>>>(V, Vt);
  hipMemsetAsync(d_out, 0, (size_t)out_size * sizeof(float), stream);

  dim3 grid(SS / 16, BB, 2);
  attn_main_kernel<<<grid, 512, 0, stream>>>(Qb, Kb, Vt, mask, mode_ptr, (float*)d_out);
}